// Round 4
// baseline (290.561 us; speedup 1.0000x reference)
//
#include <hip/hip_runtime.h>
#include <cstdint>

#define B 64
#define L 512
#define EMB 400
#define KPAD 416
#define H 256
#define NL 3
#define NE 512
#define MAXA 32
#define M_TOT (B * L)

typedef unsigned short u16;
typedef float f32x4 __attribute__((ext_vector_type(4)));
typedef short short8 __attribute__((ext_vector_type(8)));
typedef u16 u16x8 __attribute__((ext_vector_type(8)));

__device__ __forceinline__ float b2f(u16 u) {
  unsigned v = ((unsigned)u) << 16;
  return __builtin_bit_cast(float, v);
}
__device__ __forceinline__ u16 f2b(float f) {
  unsigned u = __builtin_bit_cast(unsigned, f);
  unsigned r = (u + 0x7fffu + ((u >> 16) & 1u)) >> 16;
  return (u16)r;
}

#define GL16(g, l)                                                              \
  __builtin_amdgcn_global_load_lds((const __attribute__((address_space(1))) void*)(g), \
                                   (__attribute__((address_space(3))) void*)(l), 16, 0, 0)

// ---------------------------------------------------------------------------
// bf16 MFMA GEMM, BM=64 x BN=256 (full H), BK=32, 256 threads = 4 waves (1x4).
// Wave w computes 64m x 64n at col-offset w*64: 4x4 f32x4 fragments.
// Grid = M_TOT/64 = 512 blocks (2/CU). A is read exactly once per element.
// EPI 0: conv    — A staged via global_load_lds from A0; plain bf16 store.
// EPI 1: highway — dual-B (gate+lin) MFMA; A-tiles stashed in LDS (Xl) so the
//                  residual x in the epilogue needs no global re-read.
// EPI 2: gcn     — A staged by register GATHER (h[row] + sum of bitmap
//                  neighbors, fp32 accum, f2b) -> linear ds_write_b128;
//                  epilogue relu((acc+2b)*rden), yv += out . cw, store Out.
// EPI 3: gcn, last layer — same but no Out store (dead output).
// ---------------------------------------------------------------------------
template <int EPI>
__global__ __launch_bounds__(256, 2) void gemm64(
    const u16* __restrict__ A, const u16* __restrict__ Bw, const u16* __restrict__ B2w,
    const int K,
    const float* __restrict__ bias1, const float* __restrict__ bias2,
    const unsigned* __restrict__ bmp, const float* __restrict__ rden,
    const float* __restrict__ cw, float* __restrict__ yv, u16* __restrict__ Out) {
  constexpr bool HW = (EPI == 1);
  constexpr bool GCN = (EPI >= 2);
  __shared__ u16 Al[64 * 32];                  // 4 KB
  __shared__ u16 Bl[256 * 32];                 // 16 KB
  __shared__ u16 Cl[HW ? 256 * 32 : 8];        // 16 KB (highway only)
  __shared__ u16 Xl[HW ? 64 * 256 : 8];        // 32 KB (highway only)

  const int t = threadIdx.x;
  const int wid = t >> 6, lane = t & 63;
  const int m0 = blockIdx.x * 64;
  const int fr = lane & 15, kg = lane >> 4;
  const int r4 = t >> 2, ksg = t & 3;
  const int bb = m0 >> 9;  // batch index (128 rows per block all in one batch? 64 rows -> yes)

  // gcn: keep this thread's row bitmap in registers (row m0 + r4)
  unsigned bmv[16];
  if constexpr (GCN) {
    const unsigned* p = bmp + (size_t)(m0 + r4) * 16;
#pragma unroll
    for (int i = 0; i < 16; ++i) bmv[i] = p[i];
  }

  f32x4 acc[4][4] = {};
  f32x4 acc2[4][4] = {};

  const int nk = K >> 5;
  for (int kk = 0; kk < nk; ++kk) {
    const int kc = kk * 32 + ksg * 8;
    // B staging: 256 rows x 32k = 1024 chunks, 4 global_load_lds per wave
#pragma unroll
    for (int c = 0; c < 4; ++c)
      GL16(Bw + (size_t)(c * 64 + r4) * K + kc, Bl + (size_t)(c * 256 + wid * 64) * 8);
    if constexpr (HW) {
#pragma unroll
      for (int c = 0; c < 4; ++c)
        GL16(B2w + (size_t)(c * 64 + r4) * K + kc, Cl + (size_t)(c * 256 + wid * 64) * 8);
    }
    // A staging
    if constexpr (!GCN) {
      GL16(A + (size_t)(m0 + r4) * K + kc, Al + (size_t)(wid * 64) * 8);
    } else {
      float a[8];
      const u16x8 v = *(const u16x8*)(A + (size_t)(m0 + r4) * H + kc);
#pragma unroll
      for (int i = 0; i < 8; ++i) a[i] = b2f(v[i]);
#pragma unroll
      for (int wi = 0; wi < 16; ++wi) {
        unsigned bits = bmv[wi];
        while (bits) {
          const int bit = __ffs(bits) - 1;
          bits &= bits - 1;
          const u16x8 u = *(const u16x8*)(A + (size_t)(bb * L + wi * 32 + bit) * H + kc);
#pragma unroll
          for (int i = 0; i < 8; ++i) a[i] += b2f(u[i]);
        }
      }
      u16x8 o;
#pragma unroll
      for (int i = 0; i < 8; ++i) o[i] = f2b(a[i]);
      *(u16x8*)(Al + (size_t)t * 8) = o;  // chunk t = (r4*4 + ksg): linear, conflict-free
    }
    __syncthreads();

    if constexpr (HW) {  // stash A k-tile for the epilogue residual
      const u16x8 xv = *(const u16x8*)(Al + (size_t)t * 8);
      *(u16x8*)(Xl + (size_t)(kk * 256 + t) * 8) = xv;
    }

    short8 af[4], bf[4], cf[4];
#pragma unroll
    for (int i = 0; i < 4; ++i) {
      af[i] = *(const short8*)(Al + ((size_t)(i * 16 + fr) * 4 + kg) * 8);
      bf[i] = *(const short8*)(Bl + ((size_t)(wid * 64 + i * 16 + fr) * 4 + kg) * 8);
      if constexpr (HW)
        cf[i] = *(const short8*)(Cl + ((size_t)(wid * 64 + i * 16 + fr) * 4 + kg) * 8);
    }
#pragma unroll
    for (int mi = 0; mi < 4; ++mi)
#pragma unroll
      for (int ni = 0; ni < 4; ++ni) {
        acc[mi][ni] = __builtin_amdgcn_mfma_f32_16x16x32_bf16(af[mi], bf[ni], acc[mi][ni], 0, 0, 0);
        if constexpr (HW)
          acc2[mi][ni] =
              __builtin_amdgcn_mfma_f32_16x16x32_bf16(af[mi], cf[ni], acc2[mi][ni], 0, 0, 0);
      }
    __syncthreads();
  }

  // epilogue: C/D mapping col = lane&15, row = (lane>>4)*4 + reg [m89-verified]
  const int r0 = kg * 4;
  const int c0 = wid * 64 + fr;
  if constexpr (EPI == 0) {
#pragma unroll
    for (int ni = 0; ni < 4; ++ni) {
      const int col = c0 + ni * 16;
#pragma unroll
      for (int mi = 0; mi < 4; ++mi)
#pragma unroll
        for (int rr = 0; rr < 4; ++rr)
          Out[(size_t)(m0 + mi * 16 + r0 + rr) * H + col] = f2b(acc[mi][ni][rr]);
    }
  } else if constexpr (EPI == 1) {
#pragma unroll
    for (int ni = 0; ni < 4; ++ni) {
      const int col = c0 + ni * 16;
      const float b1 = bias1[col], b2 = bias2[col];
      const int xbase = (col >> 5) * 2048 + (col & 31);
#pragma unroll
      for (int mi = 0; mi < 4; ++mi)
#pragma unroll
        for (int rr = 0; rr < 4; ++rr) {
          const int rl = mi * 16 + r0 + rr;
          const float g = 1.f / (1.f + __expf(-(acc[mi][ni][rr] + b1)));
          const float nn = acc2[mi][ni][rr] + b2;
          const float x = b2f(Xl[xbase + rl * 32]);
          Out[(size_t)(m0 + rl) * H + col] = f2b(g * nn + (1.f - g) * x);
        }
    }
  } else {
    float ypart[16];
#pragma unroll
    for (int q = 0; q < 16; ++q) ypart[q] = 0.f;
#pragma unroll
    for (int ni = 0; ni < 4; ++ni) {
      const int col = c0 + ni * 16;
      const float b1 = 2.f * bias1[col];
      const float cwv = cw[col];
#pragma unroll
      for (int mi = 0; mi < 4; ++mi)
#pragma unroll
        for (int rr = 0; rr < 4; ++rr) {
          const int row = m0 + mi * 16 + r0 + rr;
          const float s = (acc[mi][ni][rr] + b1) * rden[row];
          const float rl = s > 0.f ? s : 0.f;
          ypart[mi * 4 + rr] += rl * cwv;
          if constexpr (EPI == 2) Out[(size_t)row * H + col] = f2b(rl);
        }
    }
#pragma unroll
    for (int q = 0; q < 16; ++q) {
      float p = ypart[q];
      p += __shfl_xor(p, 1);
      p += __shfl_xor(p, 2);
      p += __shfl_xor(p, 4);
      p += __shfl_xor(p, 8);
      if (fr == 0) atomicAdd(&yv[m0 + (q >> 2) * 16 + r0 + (q & 3)], p);
    }
  }
}

// ---------------------------------------------------------------------------
// Semb [B][EMB][L] fp32 -> A0 [B*L][KPAD] bf16 (transpose + pad 400->416)
// ---------------------------------------------------------------------------
__global__ __launch_bounds__(256) void k_sembT(const float* __restrict__ Semb,
                                               u16* __restrict__ A0) {
  const int b = blockIdx.x, e0 = blockIdx.y * 64, l0 = blockIdx.z * 64;
  __shared__ u16 tile[64][72];
  const int t = threadIdx.x;
  {
    const int er = t >> 2, ls = (t & 3) * 16;
    if (e0 + er < EMB) {
      const float* src = Semb + ((size_t)b * EMB + e0 + er) * L + l0 + ls;
#pragma unroll
      for (int i = 0; i < 4; ++i) {
        const float4 v = *(const float4*)(src + i * 4);
        tile[er][ls + i * 4 + 0] = f2b(v.x);
        tile[er][ls + i * 4 + 1] = f2b(v.y);
        tile[er][ls + i * 4 + 2] = f2b(v.z);
        tile[er][ls + i * 4 + 3] = f2b(v.w);
      }
    } else {
#pragma unroll
      for (int i = 0; i < 16; ++i) tile[er][ls + i] = 0;
    }
  }
  __syncthreads();
  {
    const int lr = t >> 2, es = (t & 3) * 16;
    if (e0 + es < KPAD) {
      u16x8 v0, v1;
#pragma unroll
      for (int i = 0; i < 8; ++i) v0[i] = tile[es + i][lr];
#pragma unroll
      for (int i = 0; i < 8; ++i) v1[i] = tile[es + 8 + i][lr];
      u16* dst = A0 + (size_t)(b * L + l0 + lr) * KPAD + e0 + es;
      *(u16x8*)dst = v0;
      *(u16x8*)(dst + 8) = v1;
    }
  }
}

// all weight conversions in one dispatch
__global__ void k_cvtall(const float* __restrict__ W1, const float* __restrict__ gW,
                         const float* __restrict__ lW, const float* __restrict__ gcnW,
                         u16* __restrict__ W1b, u16* __restrict__ HWGb,
                         u16* __restrict__ HWLb, u16* __restrict__ GCNb) {
  int i = blockIdx.x * 256 + threadIdx.x;
  if (i < 256 * KPAD) {
    const int o = i / KPAD, k = i - o * KPAD;
    W1b[i] = (k < EMB) ? f2b(W1[o * EMB + k]) : (u16)0;
    return;
  }
  i -= 256 * KPAD;
  if (i < 2 * H * H) { HWGb[i] = f2b(gW[i]); return; }
  i -= 2 * H * H;
  if (i < 2 * H * H) { HWLb[i] = f2b(lW[i]); return; }
  i -= 2 * H * H;
  if (i < NL * H * H) GCNb[i] = f2b(gcnW[i]);
}

// dedup'd adjacency bitmap
__global__ void k_edges(const int* __restrict__ edges, unsigned* __restrict__ bm) {
  const int t = blockIdx.x * 256 + threadIdx.x;
  const int b = t >> 9, e = t & 511;
  const int u = edges[(size_t)(b * NE + e) * 2 + 0];
  const int v = edges[(size_t)(b * NE + e) * 2 + 1];
  atomicOr(&bm[(size_t)(b * L + u) * 16 + (v >> 5)], 1u << (v & 31));
  atomicOr(&bm[(size_t)(b * L + v) * 16 + (u >> 5)], 1u << (u & 31));
}

__global__ void k_rden(const unsigned* __restrict__ bm, float* __restrict__ rden) {
  const int m = blockIdx.x * 256 + threadIdx.x;
  const uint4* p = (const uint4*)(bm + (size_t)m * 16);
  int c = 0;
#pragma unroll
  for (int w = 0; w < 4; ++w) {
    const uint4 v = p[w];
    c += __popc(v.x) + __popc(v.y) + __popc(v.z) + __popc(v.w);
  }
  rden[m] = 1.f / (1.f + (float)c);
}

// logits + maskA: block 128 does maskA, blocks 0..127 do logits
__global__ __launch_bounds__(256) void k_logits(const float* __restrict__ yv,
                                                const float* __restrict__ cb,
                                                const float* __restrict__ lw,
                                                const float* __restrict__ lb,
                                                const int* __restrict__ wids,
                                                const int* __restrict__ y1,
                                                const int* __restrict__ y2,
                                                float* __restrict__ out) {
  if (blockIdx.x == B * 2) {
#pragma unroll
    for (int j = 0; j < 8; ++j) {
      const int idx = j * 256 + threadIdx.x;  // < B*MAXA
      const int b = idx >> 5, q = idx & 31;
      out[B * L + idx] = (y1[b] + q <= y2[b]) ? 1.0f : 0.0f;
    }
    return;
  }
  const int b = blockIdx.x >> 1;
  const int m = ((blockIdx.x & 1) << 8) + threadIdx.x;
  __shared__ float ys[512];
  const float cb0 = cb[0];
  ys[threadIdx.x] = fmaxf(yv[(size_t)b * L + threadIdx.x] + cb0, 0.f);
  ys[threadIdx.x + 256] = fmaxf(yv[(size_t)b * L + 256 + threadIdx.x] + cb0, 0.f);
  __syncthreads();
  float acc = lb[m];
  const float4* wr = (const float4*)(lw + (size_t)m * L);
#pragma unroll 4
  for (int l4 = 0; l4 < 128; ++l4) {
    const float4 w4 = wr[l4];
    acc += ys[l4 * 4] * w4.x + ys[l4 * 4 + 1] * w4.y + ys[l4 * 4 + 2] * w4.z +
           ys[l4 * 4 + 3] * w4.w;
  }
  out[(size_t)b * L + m] = (wids[(size_t)b * L + m] != 0) ? acc : -1.0e30f;
}

extern "C" void kernel_launch(void* const* d_in, const int* in_sizes, int n_in,
                              void* d_out, int out_size, void* d_ws, size_t ws_size,
                              hipStream_t stream) {
  (void)in_sizes; (void)n_in; (void)out_size; (void)ws_size;
  const float* Semb      = (const float*)d_in[0];
  const int*   wids      = (const int*)d_in[1];
  const int*   y1        = (const int*)d_in[2];
  const int*   y2        = (const int*)d_in[3];
  const int*   edges     = (const int*)d_in[4];
  const float* W1        = (const float*)d_in[5];
  const float* hw_lin_W  = (const float*)d_in[6];
  const float* hw_lin_b  = (const float*)d_in[7];
  const float* hw_gate_W = (const float*)d_in[8];
  const float* hw_gate_b = (const float*)d_in[9];
  const float* gcn_W     = (const float*)d_in[10];
  const float* gcn_b     = (const float*)d_in[11];
  const float* conv_W    = (const float*)d_in[12];
  const float* conv_b    = (const float*)d_in[13];
  const float* lin_W     = (const float*)d_in[14];
  const float* lin_b     = (const float*)d_in[15];
  float* out = (float*)d_out;

  char* ws = (char*)d_ws;
  const size_t SZA = (size_t)M_TOT * KPAD * 2;   // 27,262,976
  const size_t SZX = (size_t)M_TOT * H * 2;      // 16,777,216
  u16* A0   = (u16*)(ws);
  u16* P0b  = (u16*)(ws + SZA);
  u16* P1b  = (u16*)(ws + SZA + SZX);
  u16* O0   = (u16*)(ws + SZA + 2 * SZX);
  u16* O1   = (u16*)(ws + SZA + 3 * SZX);
  char* wp  = ws + SZA + 4 * SZX;
  u16* W1b  = (u16*)(wp);                         // 212,992
  u16* HWGb = (u16*)(wp + 212992);                // 262,144
  u16* HWLb = (u16*)(wp + 212992 + 262144);       // 262,144
  u16* GCNb = (u16*)(wp + 212992 + 2 * 262144);   // 393,216
  char* sp  = wp + 212992 + 2 * 262144 + 393216;
  unsigned* bm   = (unsigned*)(sp);               // 2 MB
  float*    yv   = (float*)(sp + 2097152);        // 128 KB (zeroed w/ bm)
  float*    rden = (float*)(sp + 2097152 + 131072);

  // adjacency + yv accumulator init (one memset covers bm and yv)
  hipMemsetAsync(bm, 0, 2097152 + 131072, stream);
  k_edges<<<dim3(B * NE / 256), 256, 0, stream>>>(edges, bm);
  k_rden<<<dim3(B * L / 256), 256, 0, stream>>>(bm, rden);

  // conversions (one dispatch) + transpose
  k_cvtall<<<dim3((256 * KPAD + 4 * H * H + NL * H * H + 255) / 256), 256, 0, stream>>>(
      W1, hw_gate_W, hw_lin_W, gcn_W, W1b, HWGb, HWLb, GCNb);
  k_sembT<<<dim3(B, 7, 8), 256, 0, stream>>>(Semb, A0);

  // conv 1x1
  gemm64<0><<<dim3(M_TOT / 64), 256, 0, stream>>>(A0, W1b, nullptr, KPAD, nullptr, nullptr,
                                                  nullptr, nullptr, nullptr, nullptr, P0b);
  // highway x2 (gate + lin fused, residual from LDS)
  gemm64<1><<<dim3(M_TOT / 64), 256, 0, stream>>>(P0b, HWGb, HWLb, H, hw_gate_b, hw_lin_b,
                                                  nullptr, nullptr, nullptr, nullptr, P1b);
  gemm64<1><<<dim3(M_TOT / 64), 256, 0, stream>>>(P1b, HWGb + H * H, HWLb + H * H, H,
                                                  hw_gate_b + H, hw_lin_b + H, nullptr, nullptr,
                                                  nullptr, nullptr, P0b);
  // GCN layers with fused gather (and fused yv accumulation)
  gemm64<2><<<dim3(M_TOT / 64), 256, 0, stream>>>(P0b, GCNb, nullptr, H, gcn_b, nullptr,
                                                  bm, rden, conv_W, yv, O0);
  gemm64<2><<<dim3(M_TOT / 64), 256, 0, stream>>>(O0, GCNb + H * H, nullptr, H, gcn_b + H,
                                                  nullptr, bm, rden, conv_W + H, yv, O1);
  gemm64<3><<<dim3(M_TOT / 64), 256, 0, stream>>>(O1, GCNb + 2 * H * H, nullptr, H,
                                                  gcn_b + 2 * H, nullptr, bm, rden,
                                                  conv_W + 2 * H, yv, nullptr);

  // head (+ maskA in the extra block)
  k_logits<<<dim3(B * 2 + 1), 256, 0, stream>>>(yv, conv_b, lin_W, lin_b, wids, y1, y2, out);
}

// Round 6
// 226.035 us; speedup vs baseline: 1.2855x; 1.2855x over previous
//
#include <hip/hip_runtime.h>
#include <cstdint>

#define B 64
#define L 512
#define EMB 400
#define KPAD 416
#define H 256
#define NL 3
#define NE 512
#define MAXA 32
#define M_TOT (B * L)

typedef unsigned short u16;
typedef float f32x4 __attribute__((ext_vector_type(4)));
typedef short short8 __attribute__((ext_vector_type(8)));
typedef u16 u16x8 __attribute__((ext_vector_type(8)));

__device__ __forceinline__ float b2f(u16 u) {
  unsigned v = ((unsigned)u) << 16;
  return __builtin_bit_cast(float, v);
}
__device__ __forceinline__ u16 f2b(float f) {
  unsigned u = __builtin_bit_cast(unsigned, f);
  unsigned r = (u + 0x7fffu + ((u >> 16) & 1u)) >> 16;
  return (u16)r;
}

#define GL16(g, l)                                                              \
  __builtin_amdgcn_global_load_lds((const __attribute__((address_space(1))) void*)(g), \
                                   (__attribute__((address_space(3))) void*)(l), 16, 0, 0)

// ---------------------------------------------------------------------------
// bf16 MFMA GEMM, BM=64 x BN=256 (full H), BK=32, 256 threads = 4 waves (1x4).
// Wave w computes 64m x 64n at col-offset w*64; 4x4 f32x4 fragments.
// Grid = M_TOT/64 = 512 blocks (2/CU). A read exactly once per element.
// EPI 0: conv    — A staged via global_load_lds; plain bf16 store.
// EPI 1: highway — dual-B (gate+lin); A k-tiles stashed in Xl for residual.
// EPI 2: gcn     — A PRE-GATHERED once into LDS (h[row]+sum neighbors, fp32
//                  accum) in MFMA chunk layout; k-loop = B-stage + MFMA only.
//                  Pre-gather: 4 passes, rr=(t>>4)+p*16, s=t&15 -> covers the
//                  FULL 64x256 tile (r5 bug: 2 passes covered only k<128).
//                  Epilogue relu((acc+2b)*rden), yv += out.cw, store Out.
// EPI 3: gcn last layer — no Out store (dead output).
// ---------------------------------------------------------------------------
template <int EPI>
__global__ __launch_bounds__(256, 2) void gemm64(
    const u16* __restrict__ A, const u16* __restrict__ Bw, const u16* __restrict__ B2w,
    const int K,
    const float* __restrict__ bias1, const float* __restrict__ bias2,
    const unsigned* __restrict__ bmp, const float* __restrict__ rden,
    const float* __restrict__ cw, float* __restrict__ yv, u16* __restrict__ Out) {
  constexpr bool HW = (EPI == 1);
  constexpr bool GCN = (EPI >= 2);
  __shared__ u16 Bl[256 * 32];                           // 16 KB
  __shared__ u16 Al[GCN ? 8 : 64 * 32];                  // 4 KB (conv/HW)
  __shared__ u16 Cl[HW ? 256 * 32 : 8];                  // 16 KB (HW)
  __shared__ u16 Xl[(HW || GCN) ? 64 * 256 : 8];         // 32 KB (HW stash / GCN A-tile)

  const int t = threadIdx.x;
  const int wid = t >> 6, lane = t & 63;
  const int m0 = blockIdx.x * 64;
  const int fr = lane & 15, kg = lane >> 4;
  const int r4 = t >> 2, ksg = t & 3;
  const int bb = m0 >> 9;  // batch index (64 rows per block, 512 rows/batch)

  // GCN: pre-gather this block's 64 T-rows into Xl (chunk layout), once.
  // 4 passes; thread handles row (t>>4)+p*16, 32B segment s=t&15 (16 u16).
  // k = s*16 + j  ->  kk = s>>1 in [0,8), chunk ((kk*64+rr)*4 + (s&1)*2)+{0,1}
  if constexpr (GCN) {
#pragma unroll
    for (int p = 0; p < 4; ++p) {
      const int rr = (t >> 4) + p * 16;
      const int s = t & 15;
      const int grow = m0 + rr;
      const unsigned* bp = bmp + (size_t)grow * 16;
      const u16* src = A + (size_t)grow * H + s * 16;
      float a[16];
      {
        const u16x8 v0 = *(const u16x8*)(src);
        const u16x8 v1 = *(const u16x8*)(src + 8);
#pragma unroll
        for (int i = 0; i < 8; ++i) { a[i] = b2f(v0[i]); a[8 + i] = b2f(v1[i]); }
      }
#pragma unroll
      for (int wi = 0; wi < 16; ++wi) {
        unsigned bits = bp[wi];
        while (bits) {
          const int bit = __ffs(bits) - 1;
          bits &= bits - 1;
          const u16* ns = A + (size_t)(bb * L + wi * 32 + bit) * H + s * 16;
          const u16x8 n0 = *(const u16x8*)ns;
          const u16x8 n1 = *(const u16x8*)(ns + 8);
#pragma unroll
          for (int i = 0; i < 8; ++i) { a[i] += b2f(n0[i]); a[8 + i] += b2f(n1[i]); }
        }
      }
      u16x8 o0, o1;
#pragma unroll
      for (int i = 0; i < 8; ++i) { o0[i] = f2b(a[i]); o1[i] = f2b(a[8 + i]); }
      u16* dst = Xl + ((size_t)((s >> 1) * 64 + rr) * 4 + (s & 1) * 2) * 8;
      *(u16x8*)dst = o0;
      *(u16x8*)(dst + 8) = o1;
    }
    __syncthreads();
  }

  f32x4 acc[4][4] = {};
  f32x4 acc2[4][4] = {};

  const int nk = K >> 5;
  for (int kk = 0; kk < nk; ++kk) {
    const int kc = kk * 32 + ksg * 8;
    // B staging: 256 rows x 32k = 1024 chunks, 4 global_load_lds per thread
#pragma unroll
    for (int c = 0; c < 4; ++c)
      GL16(Bw + (size_t)(c * 64 + r4) * K + kc, Bl + (size_t)(c * 256 + wid * 64) * 8);
    if constexpr (HW) {
#pragma unroll
      for (int c = 0; c < 4; ++c)
        GL16(B2w + (size_t)(c * 64 + r4) * K + kc, Cl + (size_t)(c * 256 + wid * 64) * 8);
    }
    if constexpr (!GCN) {
      GL16(A + (size_t)(m0 + r4) * K + kc, Al + (size_t)(wid * 64) * 8);
    }
    __syncthreads();

    if constexpr (HW) {  // stash A k-tile for the epilogue residual
      const u16x8 xv = *(const u16x8*)(Al + (size_t)t * 8);
      *(u16x8*)(Xl + (size_t)(kk * 256 + t) * 8) = xv;
    }

    short8 af[4], bf[4], cf[4];
#pragma unroll
    for (int i = 0; i < 4; ++i) {
      if constexpr (GCN)
        af[i] = *(const short8*)(Xl + ((size_t)(kk * 64 + i * 16 + fr) * 4 + kg) * 8);
      else
        af[i] = *(const short8*)(Al + ((size_t)(i * 16 + fr) * 4 + kg) * 8);
      bf[i] = *(const short8*)(Bl + ((size_t)(wid * 64 + i * 16 + fr) * 4 + kg) * 8);
      if constexpr (HW)
        cf[i] = *(const short8*)(Cl + ((size_t)(wid * 64 + i * 16 + fr) * 4 + kg) * 8);
    }
#pragma unroll
    for (int mi = 0; mi < 4; ++mi)
#pragma unroll
      for (int ni = 0; ni < 4; ++ni) {
        acc[mi][ni] = __builtin_amdgcn_mfma_f32_16x16x32_bf16(af[mi], bf[ni], acc[mi][ni], 0, 0, 0);
        if constexpr (HW)
          acc2[mi][ni] =
              __builtin_amdgcn_mfma_f32_16x16x32_bf16(af[mi], cf[ni], acc2[mi][ni], 0, 0, 0);
      }
    __syncthreads();
  }

  // epilogue: C/D mapping col = lane&15, row = (lane>>4)*4 + reg [m89-verified]
  const int r0 = kg * 4;
  const int c0 = wid * 64 + fr;
  if constexpr (EPI == 0) {
#pragma unroll
    for (int ni = 0; ni < 4; ++ni) {
      const int col = c0 + ni * 16;
#pragma unroll
      for (int mi = 0; mi < 4; ++mi)
#pragma unroll
        for (int rr = 0; rr < 4; ++rr)
          Out[(size_t)(m0 + mi * 16 + r0 + rr) * H + col] = f2b(acc[mi][ni][rr]);
    }
  } else if constexpr (EPI == 1) {
#pragma unroll
    for (int ni = 0; ni < 4; ++ni) {
      const int col = c0 + ni * 16;
      const float b1 = bias1[col], b2 = bias2[col];
      const int xbase = (col >> 5) * 2048 + (col & 31);
#pragma unroll
      for (int mi = 0; mi < 4; ++mi)
#pragma unroll
        for (int rr = 0; rr < 4; ++rr) {
          const int rl = mi * 16 + r0 + rr;
          const float g = 1.f / (1.f + __expf(-(acc[mi][ni][rr] + b1)));
          const float nn = acc2[mi][ni][rr] + b2;
          const float x = b2f(Xl[xbase + rl * 32]);
          Out[(size_t)(m0 + rl) * H + col] = f2b(g * nn + (1.f - g) * x);
        }
    }
  } else {
    float ypart[16];
#pragma unroll
    for (int q = 0; q < 16; ++q) ypart[q] = 0.f;
#pragma unroll
    for (int ni = 0; ni < 4; ++ni) {
      const int col = c0 + ni * 16;
      const float b1 = 2.f * bias1[col];
      const float cwv = cw[col];
#pragma unroll
      for (int mi = 0; mi < 4; ++mi)
#pragma unroll
        for (int rr = 0; rr < 4; ++rr) {
          const int row = m0 + mi * 16 + r0 + rr;
          const float s = (acc[mi][ni][rr] + b1) * rden[row];
          const float rl = s > 0.f ? s : 0.f;
          ypart[mi * 4 + rr] += rl * cwv;
          if constexpr (EPI == 2) Out[(size_t)row * H + col] = f2b(rl);
        }
    }
#pragma unroll
    for (int q = 0; q < 16; ++q) {
      float p = ypart[q];
      p += __shfl_xor(p, 1);
      p += __shfl_xor(p, 2);
      p += __shfl_xor(p, 4);
      p += __shfl_xor(p, 8);
      if (fr == 0) atomicAdd(&yv[m0 + (q >> 2) * 16 + r0 + (q & 3)], p);
    }
  }
}

// ---------------------------------------------------------------------------
// Semb [B][EMB][L] fp32 -> A0 [B*L][KPAD] bf16 (transpose + pad 400->416)
// ---------------------------------------------------------------------------
__global__ __launch_bounds__(256) void k_sembT(const float* __restrict__ Semb,
                                               u16* __restrict__ A0) {
  const int b = blockIdx.x, e0 = blockIdx.y * 64, l0 = blockIdx.z * 64;
  __shared__ u16 tile[64][72];
  const int t = threadIdx.x;
  {
    const int er = t >> 2, ls = (t & 3) * 16;
    if (e0 + er < EMB) {
      const float* src = Semb + ((size_t)b * EMB + e0 + er) * L + l0 + ls;
#pragma unroll
      for (int i = 0; i < 4; ++i) {
        const float4 v = *(const float4*)(src + i * 4);
        tile[er][ls + i * 4 + 0] = f2b(v.x);
        tile[er][ls + i * 4 + 1] = f2b(v.y);
        tile[er][ls + i * 4 + 2] = f2b(v.z);
        tile[er][ls + i * 4 + 3] = f2b(v.w);
      }
    } else {
#pragma unroll
      for (int i = 0; i < 16; ++i) tile[er][ls + i] = 0;
    }
  }
  __syncthreads();
  {
    const int lr = t >> 2, es = (t & 3) * 16;
    if (e0 + es < KPAD) {
      u16x8 v0, v1;
#pragma unroll
      for (int i = 0; i < 8; ++i) v0[i] = tile[es + i][lr];
#pragma unroll
      for (int i = 0; i < 8; ++i) v1[i] = tile[es + 8 + i][lr];
      u16* dst = A0 + (size_t)(b * L + l0 + lr) * KPAD + e0 + es;
      *(u16x8*)dst = v0;
      *(u16x8*)(dst + 8) = v1;
    }
  }
}

// all weight conversions in one dispatch
__global__ void k_cvtall(const float* __restrict__ W1, const float* __restrict__ gW,
                         const float* __restrict__ lW, const float* __restrict__ gcnW,
                         u16* __restrict__ W1b, u16* __restrict__ HWGb,
                         u16* __restrict__ HWLb, u16* __restrict__ GCNb) {
  int i = blockIdx.x * 256 + threadIdx.x;
  if (i < 256 * KPAD) {
    const int o = i / KPAD, k = i - o * KPAD;
    W1b[i] = (k < EMB) ? f2b(W1[o * EMB + k]) : (u16)0;
    return;
  }
  i -= 256 * KPAD;
  if (i < 2 * H * H) { HWGb[i] = f2b(gW[i]); return; }
  i -= 2 * H * H;
  if (i < 2 * H * H) { HWLb[i] = f2b(lW[i]); return; }
  i -= 2 * H * H;
  if (i < NL * H * H) GCNb[i] = f2b(gcnW[i]);
}

// dedup'd adjacency bitmap
__global__ void k_edges(const int* __restrict__ edges, unsigned* __restrict__ bm) {
  const int t = blockIdx.x * 256 + threadIdx.x;
  const int b = t >> 9, e = t & 511;
  const int u = edges[(size_t)(b * NE + e) * 2 + 0];
  const int v = edges[(size_t)(b * NE + e) * 2 + 1];
  atomicOr(&bm[(size_t)(b * L + u) * 16 + (v >> 5)], 1u << (v & 31));
  atomicOr(&bm[(size_t)(b * L + v) * 16 + (u >> 5)], 1u << (u & 31));
}

__global__ void k_rden(const unsigned* __restrict__ bm, float* __restrict__ rden) {
  const int m = blockIdx.x * 256 + threadIdx.x;
  const uint4* p = (const uint4*)(bm + (size_t)m * 16);
  int c = 0;
#pragma unroll
  for (int w = 0; w < 4; ++w) {
    const uint4 v = p[w];
    c += __popc(v.x) + __popc(v.y) + __popc(v.z) + __popc(v.w);
  }
  rden[m] = 1.f / (1.f + (float)c);
}

// logits + maskA: block B*2 does maskA, blocks 0..B*2-1 do logits
__global__ __launch_bounds__(256) void k_logits(const float* __restrict__ yv,
                                                const float* __restrict__ cb,
                                                const float* __restrict__ lw,
                                                const float* __restrict__ lb,
                                                const int* __restrict__ wids,
                                                const int* __restrict__ y1,
                                                const int* __restrict__ y2,
                                                float* __restrict__ out) {
  if (blockIdx.x == B * 2) {
#pragma unroll
    for (int j = 0; j < 8; ++j) {
      const int idx = j * 256 + threadIdx.x;  // < B*MAXA
      const int b = idx >> 5, q = idx & 31;
      out[B * L + idx] = (y1[b] + q <= y2[b]) ? 1.0f : 0.0f;
    }
    return;
  }
  const int b = blockIdx.x >> 1;
  const int m = ((blockIdx.x & 1) << 8) + threadIdx.x;
  __shared__ float ys[512];
  const float cb0 = cb[0];
  ys[threadIdx.x] = fmaxf(yv[(size_t)b * L + threadIdx.x] + cb0, 0.f);
  ys[threadIdx.x + 256] = fmaxf(yv[(size_t)b * L + 256 + threadIdx.x] + cb0, 0.f);
  __syncthreads();
  float acc = lb[m];
  const float4* wr = (const float4*)(lw + (size_t)m * L);
#pragma unroll 4
  for (int l4 = 0; l4 < 128; ++l4) {
    const float4 w4 = wr[l4];
    acc += ys[l4 * 4] * w4.x + ys[l4 * 4 + 1] * w4.y + ys[l4 * 4 + 2] * w4.z +
           ys[l4 * 4 + 3] * w4.w;
  }
  out[(size_t)b * L + m] = (wids[(size_t)b * L + m] != 0) ? acc : -1.0e30f;
}

extern "C" void kernel_launch(void* const* d_in, const int* in_sizes, int n_in,
                              void* d_out, int out_size, void* d_ws, size_t ws_size,
                              hipStream_t stream) {
  (void)in_sizes; (void)n_in; (void)out_size; (void)ws_size;
  const float* Semb      = (const float*)d_in[0];
  const int*   wids      = (const int*)d_in[1];
  const int*   y1        = (const int*)d_in[2];
  const int*   y2        = (const int*)d_in[3];
  const int*   edges     = (const int*)d_in[4];
  const float* W1        = (const float*)d_in[5];
  const float* hw_lin_W  = (const float*)d_in[6];
  const float* hw_lin_b  = (const float*)d_in[7];
  const float* hw_gate_W = (const float*)d_in[8];
  const float* hw_gate_b = (const float*)d_in[9];
  const float* gcn_W     = (const float*)d_in[10];
  const float* gcn_b     = (const float*)d_in[11];
  const float* conv_W    = (const float*)d_in[12];
  const float* conv_b    = (const float*)d_in[13];
  const float* lin_W     = (const float*)d_in[14];
  const float* lin_b     = (const float*)d_in[15];
  float* out = (float*)d_out;

  char* ws = (char*)d_ws;
  const size_t SZA = (size_t)M_TOT * KPAD * 2;   // 27,262,976
  const size_t SZX = (size_t)M_TOT * H * 2;      // 16,777,216
  u16* A0   = (u16*)(ws);
  u16* P0b  = (u16*)(ws + SZA);
  u16* P1b  = (u16*)(ws + SZA + SZX);
  u16* O0   = (u16*)(ws + SZA + 2 * SZX);
  u16* O1   = (u16*)(ws + SZA + 3 * SZX);
  char* wp  = ws + SZA + 4 * SZX;
  u16* W1b  = (u16*)(wp);                         // 212,992
  u16* HWGb = (u16*)(wp + 212992);                // 262,144
  u16* HWLb = (u16*)(wp + 212992 + 262144);       // 262,144
  u16* GCNb = (u16*)(wp + 212992 + 2 * 262144);   // 393,216
  char* sp  = wp + 212992 + 2 * 262144 + 393216;
  unsigned* bm   = (unsigned*)(sp);               // 2 MB
  float*    yv   = (float*)(sp + 2097152);        // 128 KB (zeroed w/ bm)
  float*    rden = (float*)(sp + 2097152 + 131072);

  // adjacency + yv accumulator init (one memset covers bm and yv)
  hipMemsetAsync(bm, 0, 2097152 + 131072, stream);
  k_edges<<<dim3(B * NE / 256), 256, 0, stream>>>(edges, bm);
  k_rden<<<dim3(B * L / 256), 256, 0, stream>>>(bm, rden);

  // conversions (one dispatch) + transpose
  k_cvtall<<<dim3((256 * KPAD + 4 * H * H + NL * H * H + 255) / 256), 256, 0, stream>>>(
      W1, hw_gate_W, hw_lin_W, gcn_W, W1b, HWGb, HWLb, GCNb);
  k_sembT<<<dim3(B, 7, 8), 256, 0, stream>>>(Semb, A0);

  // conv 1x1
  gemm64<0><<<dim3(M_TOT / 64), 256, 0, stream>>>(A0, W1b, nullptr, KPAD, nullptr, nullptr,
                                                  nullptr, nullptr, nullptr, nullptr, P0b);
  // highway x2 (gate + lin fused, residual from LDS)
  gemm64<1><<<dim3(M_TOT / 64), 256, 0, stream>>>(P0b, HWGb, HWLb, H, hw_gate_b, hw_lin_b,
                                                  nullptr, nullptr, nullptr, nullptr, P1b);
  gemm64<1><<<dim3(M_TOT / 64), 256, 0, stream>>>(P1b, HWGb + H * H, HWLb + H * H, H,
                                                  hw_gate_b + H, hw_lin_b + H, nullptr, nullptr,
                                                  nullptr, nullptr, P0b);
  // GCN layers: pre-gathered A, fused yv accumulation
  gemm64<2><<<dim3(M_TOT / 64), 256, 0, stream>>>(P0b, GCNb, nullptr, H, gcn_b, nullptr,
                                                  bm, rden, conv_W, yv, O0);
  gemm64<2><<<dim3(M_TOT / 64), 256, 0, stream>>>(O0, GCNb + H * H, nullptr, H, gcn_b + H,
                                                  nullptr, bm, rden, conv_W + H, yv, O1);
  gemm64<3><<<dim3(M_TOT / 64), 256, 0, stream>>>(O1, GCNb + 2 * H * H, nullptr, H,
                                                  gcn_b + 2 * H, nullptr, bm, rden,
                                                  conv_W + 2 * H, yv, nullptr);

  // head (+ maskA in the extra block)
  k_logits<<<dim3(B * 2 + 1), 256, 0, stream>>>(yv, conv_b, lin_W, lin_b, wids, y1, y2, out);
}

// Round 7
// 181.241 us; speedup vs baseline: 1.6032x; 1.2472x over previous
//
#include <hip/hip_runtime.h>
#include <cstdint>

#define B 64
#define L 512
#define EMB 400
#define KPAD 448
#define H 256
#define NL 3
#define NE 512
#define MAXA 32
#define M_TOT (B * L)

typedef unsigned short u16;
typedef float f32x4 __attribute__((ext_vector_type(4)));
typedef short short8 __attribute__((ext_vector_type(8)));
typedef u16 u16x8 __attribute__((ext_vector_type(8)));

__device__ __forceinline__ float b2f(u16 u) {
  unsigned v = ((unsigned)u) << 16;
  return __builtin_bit_cast(float, v);
}
__device__ __forceinline__ u16 f2b(float f) {
  unsigned u = __builtin_bit_cast(unsigned, f);
  unsigned r = (u + 0x7fffu + ((u >> 16) & 1u)) >> 16;
  return (u16)r;
}

#define GL16(g, l)                                                              \
  __builtin_amdgcn_global_load_lds((const __attribute__((address_space(1))) void*)(g), \
                                   (__attribute__((address_space(3))) void*)(l), 16, 0, 0)

// ---------------------------------------------------------------------------
// bf16 MFMA GEMM, BM=64 x BN=256 (full H), BK=32, 256 threads = 4 waves (1x4).
// 2-PHASE double-buffered staging: issue next k-tile's global_load_lds BEFORE
// computing current tile (distinct named LDS buffers); one __syncthreads per
// tile -> staging latency hides under MFMA (guide T3-minimum, m248).
// EPI 0: conv  (A=A0 [M][KPAD]);  EPI 1: highway dual-B, residual re-read from
// global A in epilogue; EPI 2: gcn relu((acc+2b)*rden), yv += out.cw, store;
// EPI 3: gcn last layer, yv only (dead Out elided).
// ---------------------------------------------------------------------------
template <int EPI>
__global__ __launch_bounds__(256, 2) void gemm64(
    const u16* __restrict__ A, const u16* __restrict__ Bw, const u16* __restrict__ B2w,
    const int K,
    const float* __restrict__ bias1, const float* __restrict__ bias2,
    const float* __restrict__ rden, const float* __restrict__ cw,
    float* __restrict__ yv, u16* __restrict__ Out) {
  constexpr bool HW = (EPI == 1);
  __shared__ u16 Bl0[256 * 32];
  __shared__ u16 Bl1[256 * 32];
  __shared__ u16 Al0[64 * 32];
  __shared__ u16 Al1[64 * 32];
  __shared__ u16 Cl0[HW ? 256 * 32 : 8];
  __shared__ u16 Cl1[HW ? 256 * 32 : 8];

  const int t = threadIdx.x;
  const int wid = t >> 6, lane = t & 63;
  const int m0 = blockIdx.x * 64;
  const int fr = lane & 15, kg = lane >> 4;
  const int r4 = t >> 2, ksg = t & 3;

  f32x4 acc[4][4] = {};
  f32x4 acc2[4][4] = {};

  auto stage = [&](u16* Ab, u16* Bb, u16* Cb, int kk) {
    const int kc = kk * 32 + ksg * 8;
#pragma unroll
    for (int c = 0; c < 4; ++c)
      GL16(Bw + (size_t)(c * 64 + r4) * K + kc, Bb + (size_t)(c * 256 + wid * 64) * 8);
    if constexpr (HW) {
#pragma unroll
      for (int c = 0; c < 4; ++c)
        GL16(B2w + (size_t)(c * 64 + r4) * K + kc, Cb + (size_t)(c * 256 + wid * 64) * 8);
    }
    GL16(A + (size_t)(m0 + r4) * K + kc, Ab + (size_t)(wid * 64) * 8);
  };
  auto compute = [&](const u16* Ab, const u16* Bb, const u16* Cb) {
    short8 af[4], bf[4], cf[4];
#pragma unroll
    for (int i = 0; i < 4; ++i) {
      af[i] = *(const short8*)(Ab + ((size_t)(i * 16 + fr) * 4 + kg) * 8);
      bf[i] = *(const short8*)(Bb + ((size_t)(wid * 64 + i * 16 + fr) * 4 + kg) * 8);
      if constexpr (HW)
        cf[i] = *(const short8*)(Cb + ((size_t)(wid * 64 + i * 16 + fr) * 4 + kg) * 8);
    }
#pragma unroll
    for (int mi = 0; mi < 4; ++mi)
#pragma unroll
      for (int ni = 0; ni < 4; ++ni) {
        acc[mi][ni] = __builtin_amdgcn_mfma_f32_16x16x32_bf16(af[mi], bf[ni], acc[mi][ni], 0, 0, 0);
        if constexpr (HW)
          acc2[mi][ni] =
              __builtin_amdgcn_mfma_f32_16x16x32_bf16(af[mi], cf[ni], acc2[mi][ni], 0, 0, 0);
      }
  };

  const int nk = K >> 5;  // even: 14 (conv) or 8 (HW/GCN)
  stage(Al0, Bl0, Cl0, 0);
  __syncthreads();
  for (int kk = 0; kk < nk; kk += 2) {
    if (kk + 1 < nk) stage(Al1, Bl1, Cl1, kk + 1);
    compute(Al0, Bl0, Cl0);
    __syncthreads();
    if (kk + 2 < nk) stage(Al0, Bl0, Cl0, kk + 2);
    compute(Al1, Bl1, Cl1);
    __syncthreads();
  }

  // epilogue: C/D mapping col = lane&15, row = (lane>>4)*4 + reg [m89-verified]
  const int r0 = kg * 4;
  const int c0 = wid * 64 + fr;
  if constexpr (EPI == 0) {
#pragma unroll
    for (int ni = 0; ni < 4; ++ni) {
      const int col = c0 + ni * 16;
#pragma unroll
      for (int mi = 0; mi < 4; ++mi)
#pragma unroll
        for (int rr = 0; rr < 4; ++rr)
          Out[(size_t)(m0 + mi * 16 + r0 + rr) * H + col] = f2b(acc[mi][ni][rr]);
    }
  } else if constexpr (EPI == 1) {
#pragma unroll
    for (int ni = 0; ni < 4; ++ni) {
      const int col = c0 + ni * 16;
      const float b1 = bias1[col], b2 = bias2[col];
#pragma unroll
      for (int mi = 0; mi < 4; ++mi)
#pragma unroll
        for (int rr = 0; rr < 4; ++rr) {
          const int row = m0 + mi * 16 + r0 + rr;
          const float g = 1.f / (1.f + __expf(-(acc[mi][ni][rr] + b1)));
          const float nn = acc2[mi][ni][rr] + b2;
          const float x = b2f(A[(size_t)row * K + col]);  // residual, L2-hot
          Out[(size_t)row * H + col] = f2b(g * nn + (1.f - g) * x);
        }
    }
  } else {
    float ypart[16];
#pragma unroll
    for (int q = 0; q < 16; ++q) ypart[q] = 0.f;
#pragma unroll
    for (int ni = 0; ni < 4; ++ni) {
      const int col = c0 + ni * 16;
      const float b1 = 2.f * bias1[col];
      const float cwv = cw[col];
#pragma unroll
      for (int mi = 0; mi < 4; ++mi)
#pragma unroll
        for (int rr = 0; rr < 4; ++rr) {
          const int row = m0 + mi * 16 + r0 + rr;
          const float s = (acc[mi][ni][rr] + b1) * rden[row];
          const float rl = s > 0.f ? s : 0.f;
          ypart[mi * 4 + rr] += rl * cwv;
          if constexpr (EPI == 2) Out[(size_t)row * H + col] = f2b(rl);
        }
    }
#pragma unroll
    for (int q = 0; q < 16; ++q) {
      float p = ypart[q];
      p += __shfl_xor(p, 1);
      p += __shfl_xor(p, 2);
      p += __shfl_xor(p, 4);
      p += __shfl_xor(p, 8);
      if (fr == 0) atomicAdd(&yv[m0 + (q >> 2) * 16 + r0 + (q & 3)], p);
    }
  }
}

// T[m,:] = h[m,:] + sum_{s in adj row} h[s,:]
// 8 tokens/block, 32 lanes/token, u16x8 loads; 4096 blocks -> high TLP hides
// the neighbor-walk latency (this is why it must NOT live inside the GEMM).
__global__ __launch_bounds__(256) void k_gather(const unsigned* __restrict__ bm,
                                                const u16* __restrict__ h,
                                                u16* __restrict__ T) {
  const int t = threadIdx.x;
  const int tok = blockIdx.x * 8 + (t >> 5);
  const int b = tok >> 9;
  const int c = (t & 31) * 8;
  const uint4* wp4 = (const uint4*)(bm + (size_t)tok * 16);
  const uint4 w0 = wp4[0], w1 = wp4[1], w2 = wp4[2], w3 = wp4[3];
  const unsigned wa[16] = {w0.x, w0.y, w0.z, w0.w, w1.x, w1.y, w1.z, w1.w,
                           w2.x, w2.y, w2.z, w2.w, w3.x, w3.y, w3.z, w3.w};
  float acc[8];
  {
    const u16x8 v = *(const u16x8*)(h + (size_t)tok * H + c);
#pragma unroll
    for (int i = 0; i < 8; ++i) acc[i] = b2f(v[i]);
  }
#pragma unroll
  for (int wi = 0; wi < 16; ++wi) {
    unsigned bits = wa[wi];
    while (bits) {
      const int bit = __ffs(bits) - 1;
      bits &= bits - 1;
      const int s = wi * 32 + bit;
      const u16x8 u = *(const u16x8*)(h + (size_t)(b * L + s) * H + c);
#pragma unroll
      for (int i = 0; i < 8; ++i) acc[i] += b2f(u[i]);
    }
  }
  u16x8 o;
#pragma unroll
  for (int i = 0; i < 8; ++i) o[i] = f2b(acc[i]);
  *(u16x8*)(T + (size_t)tok * H + c) = o;
}

// Semb [B][EMB][L] fp32 -> A0 [B*L][KPAD] bf16 (transpose + pad 400->448)
__global__ __launch_bounds__(256) void k_sembT(const float* __restrict__ Semb,
                                               u16* __restrict__ A0) {
  const int b = blockIdx.x, e0 = blockIdx.y * 64, l0 = blockIdx.z * 64;
  __shared__ u16 tile[64][72];
  const int t = threadIdx.x;
  {
    const int er = t >> 2, ls = (t & 3) * 16;
    if (e0 + er < EMB) {
      const float* src = Semb + ((size_t)b * EMB + e0 + er) * L + l0 + ls;
#pragma unroll
      for (int i = 0; i < 4; ++i) {
        const float4 v = *(const float4*)(src + i * 4);
        tile[er][ls + i * 4 + 0] = f2b(v.x);
        tile[er][ls + i * 4 + 1] = f2b(v.y);
        tile[er][ls + i * 4 + 2] = f2b(v.z);
        tile[er][ls + i * 4 + 3] = f2b(v.w);
      }
    } else {
#pragma unroll
      for (int i = 0; i < 16; ++i) tile[er][ls + i] = 0;
    }
  }
  __syncthreads();
  {
    const int lr = t >> 2, es = (t & 3) * 16;
    u16x8 v0, v1;
#pragma unroll
    for (int i = 0; i < 8; ++i) v0[i] = tile[es + i][lr];
#pragma unroll
    for (int i = 0; i < 8; ++i) v1[i] = tile[es + 8 + i][lr];
    u16* dst = A0 + (size_t)(b * L + l0 + lr) * KPAD + e0 + es;
    *(u16x8*)dst = v0;
    *(u16x8*)(dst + 8) = v1;
  }
}

// weight conversions + rden, one dispatch (runs after k_edges)
__global__ void k_cvtall(const float* __restrict__ W1, const float* __restrict__ gW,
                         const float* __restrict__ lW, const float* __restrict__ gcnW,
                         const unsigned* __restrict__ bm,
                         u16* __restrict__ W1b, u16* __restrict__ HWGb,
                         u16* __restrict__ HWLb, u16* __restrict__ GCNb,
                         float* __restrict__ rden) {
  int i = blockIdx.x * 256 + threadIdx.x;
  if (i < 256 * KPAD) {
    const int o = i / KPAD, k = i - o * KPAD;
    W1b[i] = (k < EMB) ? f2b(W1[o * EMB + k]) : (u16)0;
    return;
  }
  i -= 256 * KPAD;
  if (i < 2 * H * H) { HWGb[i] = f2b(gW[i]); return; }
  i -= 2 * H * H;
  if (i < 2 * H * H) { HWLb[i] = f2b(lW[i]); return; }
  i -= 2 * H * H;
  if (i < NL * H * H) { GCNb[i] = f2b(gcnW[i]); return; }
  i -= NL * H * H;
  if (i < M_TOT) {
    const uint4* p = (const uint4*)(bm + (size_t)i * 16);
    int c = 0;
#pragma unroll
    for (int w = 0; w < 4; ++w) {
      const uint4 v = p[w];
      c += __popc(v.x) + __popc(v.y) + __popc(v.z) + __popc(v.w);
    }
    rden[i] = 1.f / (1.f + (float)c);
  }
}

// dedup'd adjacency bitmap
__global__ void k_edges(const int* __restrict__ edges, unsigned* __restrict__ bm) {
  const int t = blockIdx.x * 256 + threadIdx.x;
  const int b = t >> 9, e = t & 511;
  const int u = edges[(size_t)(b * NE + e) * 2 + 0];
  const int v = edges[(size_t)(b * NE + e) * 2 + 1];
  atomicOr(&bm[(size_t)(b * L + u) * 16 + (v >> 5)], 1u << (v & 31));
  atomicOr(&bm[(size_t)(b * L + v) * 16 + (u >> 5)], 1u << (u & 31));
}

// logits + maskA: block B*2 does maskA, blocks 0..B*2-1 do logits
__global__ __launch_bounds__(256) void k_logits(const float* __restrict__ yv,
                                                const float* __restrict__ cb,
                                                const float* __restrict__ lw,
                                                const float* __restrict__ lb,
                                                const int* __restrict__ wids,
                                                const int* __restrict__ y1,
                                                const int* __restrict__ y2,
                                                float* __restrict__ out) {
  if (blockIdx.x == B * 2) {
#pragma unroll
    for (int j = 0; j < 8; ++j) {
      const int idx = j * 256 + threadIdx.x;  // < B*MAXA
      const int b = idx >> 5, q = idx & 31;
      out[B * L + idx] = (y1[b] + q <= y2[b]) ? 1.0f : 0.0f;
    }
    return;
  }
  const int b = blockIdx.x >> 1;
  const int m = ((blockIdx.x & 1) << 8) + threadIdx.x;
  __shared__ float ys[512];
  const float cb0 = cb[0];
  ys[threadIdx.x] = fmaxf(yv[(size_t)b * L + threadIdx.x] + cb0, 0.f);
  ys[threadIdx.x + 256] = fmaxf(yv[(size_t)b * L + 256 + threadIdx.x] + cb0, 0.f);
  __syncthreads();
  float acc = lb[m];
  const float4* wr = (const float4*)(lw + (size_t)m * L);
#pragma unroll 4
  for (int l4 = 0; l4 < 128; ++l4) {
    const float4 w4 = wr[l4];
    acc += ys[l4 * 4] * w4.x + ys[l4 * 4 + 1] * w4.y + ys[l4 * 4 + 2] * w4.z +
           ys[l4 * 4 + 3] * w4.w;
  }
  out[(size_t)b * L + m] = (wids[(size_t)b * L + m] != 0) ? acc : -1.0e30f;
}

extern "C" void kernel_launch(void* const* d_in, const int* in_sizes, int n_in,
                              void* d_out, int out_size, void* d_ws, size_t ws_size,
                              hipStream_t stream) {
  (void)in_sizes; (void)n_in; (void)out_size; (void)ws_size;
  const float* Semb      = (const float*)d_in[0];
  const int*   wids      = (const int*)d_in[1];
  const int*   y1        = (const int*)d_in[2];
  const int*   y2        = (const int*)d_in[3];
  const int*   edges     = (const int*)d_in[4];
  const float* W1        = (const float*)d_in[5];
  const float* hw_lin_W  = (const float*)d_in[6];
  const float* hw_lin_b  = (const float*)d_in[7];
  const float* hw_gate_W = (const float*)d_in[8];
  const float* hw_gate_b = (const float*)d_in[9];
  const float* gcn_W     = (const float*)d_in[10];
  const float* gcn_b     = (const float*)d_in[11];
  const float* conv_W    = (const float*)d_in[12];
  const float* conv_b    = (const float*)d_in[13];
  const float* lin_W     = (const float*)d_in[14];
  const float* lin_b     = (const float*)d_in[15];
  float* out = (float*)d_out;

  char* ws = (char*)d_ws;
  const size_t SZA = (size_t)M_TOT * KPAD * 2;   // 14,680,064
  const size_t SZX = (size_t)M_TOT * H * 2;      // 16,777,216
  u16* A0   = (u16*)(ws);
  u16* P0b  = (u16*)(ws + SZA);
  u16* P1b  = (u16*)(ws + SZA + SZX);
  u16* O0   = (u16*)(ws + SZA + 2 * SZX);
  u16* O1   = (u16*)(ws + SZA + 3 * SZX);
  char* wp  = ws + SZA + 4 * SZX;
  u16* W1b  = (u16*)(wp);                         // 256*448*2 = 229,376
  u16* HWGb = (u16*)(wp + 229376);                // 262,144
  u16* HWLb = (u16*)(wp + 229376 + 262144);       // 262,144
  u16* GCNb = (u16*)(wp + 229376 + 2 * 262144);   // 393,216
  char* sp  = wp + 229376 + 2 * 262144 + 393216;
  unsigned* bm   = (unsigned*)(sp);               // 2 MB
  float*    yv   = (float*)(sp + 2097152);        // 128 KB (zeroed w/ bm)
  float*    rden = (float*)(sp + 2097152 + 131072);

  // adjacency + yv accumulator init (one memset covers bm and yv)
  hipMemsetAsync(bm, 0, 2097152 + 131072, stream);
  k_edges<<<dim3(B * NE / 256), 256, 0, stream>>>(edges, bm);

  // weight conversions + rden (after k_edges), then input transpose
  const int ncvt = 256 * KPAD + 4 * H * H + NL * H * H + M_TOT;
  k_cvtall<<<dim3((ncvt + 255) / 256), 256, 0, stream>>>(W1, hw_gate_W, hw_lin_W, gcn_W, bm,
                                                         W1b, HWGb, HWLb, GCNb, rden);
  k_sembT<<<dim3(B, KPAD / 64, 8), 256, 0, stream>>>(Semb, A0);

  // conv 1x1
  gemm64<0><<<dim3(M_TOT / 64), 256, 0, stream>>>(A0, W1b, nullptr, KPAD, nullptr, nullptr,
                                                  nullptr, nullptr, nullptr, P0b);
  // highway x2 (gate + lin fused; residual re-read from A)
  gemm64<1><<<dim3(M_TOT / 64), 256, 0, stream>>>(P0b, HWGb, HWLb, H, hw_gate_b, hw_lin_b,
                                                  nullptr, nullptr, nullptr, P1b);
  gemm64<1><<<dim3(M_TOT / 64), 256, 0, stream>>>(P1b, HWGb + H * H, HWLb + H * H, H,
                                                  hw_gate_b + H, hw_lin_b + H, nullptr, nullptr,
                                                  nullptr, P0b);
  // GCN layers: separate high-TLP gather, then plain-A GEMM w/ fused yv
  k_gather<<<dim3(M_TOT / 8), 256, 0, stream>>>(bm, P0b, P1b);
  gemm64<2><<<dim3(M_TOT / 64), 256, 0, stream>>>(P1b, GCNb, nullptr, H, gcn_b, nullptr,
                                                  rden, conv_W, yv, O0);
  k_gather<<<dim3(M_TOT / 8), 256, 0, stream>>>(bm, O0, P0b);
  gemm64<2><<<dim3(M_TOT / 64), 256, 0, stream>>>(P0b, GCNb + H * H, nullptr, H, gcn_b + H,
                                                  nullptr, rden, conv_W + H, yv, O1);
  k_gather<<<dim3(M_TOT / 8), 256, 0, stream>>>(bm, O1, P1b);
  gemm64<3><<<dim3(M_TOT / 64), 256, 0, stream>>>(P1b, GCNb + 2 * H * H, nullptr, H,
                                                  gcn_b + 2 * H, nullptr, rden,
                                                  conv_W + 2 * H, yv, nullptr);

  // head (+ maskA in the extra block)
  k_logits<<<dim3(B * 2 + 1), 256, 0, stream>>>(yv, conv_b, lin_W, lin_b, wids, y1, y2, out);
}